// Round 3
// baseline (483.031 us; speedup 1.0000x reference)
//
#include <hip/hip_runtime.h>

// KanvolutionLayer: out[b,o,hw] = (sum_{p,c} x^(p+1) Wp[p,o,c] + bp[o]) / (1 + |sum_{q,c} x^(q+1) Wq[q,o,c]|)
// MFMA GEMM, M=100352 (b*hw), K=1280 (p*256+c), N=512 (p/q outs interleaved per 16).
// R4: 128x128 block, 64x64/wave -> 2 blocks/CU, MfmaUtil 33%, 401 us.
// R5: LDS-A + volatile -> acc spilled to scratch (WRITE 3.5GB). Lesson: shrink per-wave tile.
// R6: 128x64 block, 32x64/wave, 9x4KB slabs all-LDS, 3 blocks/CU: 383 us. PMC: VALUBusy 47 +
//     MfmaUtil 36.5 + ~16% bubbles = 100% -> pipes run SERIALLY; VALU work is the bigger term.
// R7: overlap + VALU diet.
//  - launch_bounds(256,4): regs 84+32acc=116 <= 128, LDS 4x36864=144KB <= 160 -> 4 blocks/CU;
//    4 independent blocks/SIMD = role-diverse waves.
//  - s_setprio(1) around each p-step's MFMA cluster (T5 positive regime: independent blocks).
//  - power state xv/pw/xn as float2 vectors -> v_pk_mul_f32 / v_pk_add_f32 (VOP3P packed fp32)
//    for the power-update and residual-subtract: ~130 of ~316 VALU instr/g halved.

typedef __attribute__((ext_vector_type(8))) short bf16x8;           // MFMA A/B frag (4 VGPRs)
typedef __attribute__((ext_vector_type(4))) float f32x4;            // MFMA C/D frag
typedef __attribute__((ext_vector_type(2))) float f32x2;            // packed-fp32 pair

#define CIN    256
#define HW3    3136          // 56*56
#define MTOT   100352        // 32*3136 = 784 * 128
#define KTOT   1280
#define WPLANE (512 * 1280)

__device__ __forceinline__ unsigned short f2bf(float f) {
    union { float f; unsigned int u; } cv; cv.f = f;
    unsigned int u = cv.u;
    return (unsigned short)((u + 0x7FFFu + ((u >> 16) & 1u)) >> 16);  // RNE
}
__device__ __forceinline__ float bf2f(unsigned short h) {
    union { unsigned int u; float f; } cv; cv.u = ((unsigned int)h) << 16;
    return cv.f;
}

// Pack weights into bf16 hi/lo planes [512][1280]; row n -> (o,isq):
//   o = (n>>5)*16 + (n&15), isq = (n>>4)&1  (pairs P/Q frags per 16 cols). k = p*256 + c.
__global__ void pack_w_kernel(const float* __restrict__ Wp,
                              const float* __restrict__ Wq,
                              unsigned short* __restrict__ Whi,
                              unsigned short* __restrict__ Wlo) {
    int idx = blockIdx.x * 256 + threadIdx.x;      // [0, 512*1280)
    int n = idx / KTOT;
    int k = idx - n * KTOT;
    int p = k >> 8, c = k & 255;
    int o = ((n >> 5) << 4) + (n & 15);
    int isq = (n >> 4) & 1;
    float v;
    if (isq) v = (p < 4) ? Wq[((size_t)p * 256 + o) * 256 + c] : 0.0f;
    else     v = Wp[((size_t)p * 256 + o) * 256 + c];
    unsigned short h = f2bf(v);
    Whi[idx] = h;
    Wlo[idx] = f2bf(v - bf2f(h));   // exact residual, then one rounding
}

__device__ __forceinline__ unsigned int fbits(float f) {
    union { float f; unsigned int u; } c; c.f = f; return c.u;
}
__device__ __forceinline__ float ubits(unsigned int u) {
    union { unsigned int u; float f; } c; c.u = u; return c.f;
}

// Pack top-16 bits of 4 f32x2 (8 fp32) into a bf16x8 frag (truncation) via v_perm_b32.
__device__ __forceinline__ bf16x8 pack_hi8v(const f32x2* p) {
    union { unsigned int w[4]; bf16x8 h; } r;
#pragma unroll
    for (int j = 0; j < 4; ++j)
        r.w[j] = __builtin_amdgcn_perm(fbits(p[j].y), fbits(p[j].x), 0x07060302);
    return r.h;
}
// Exact residual v - trunc16(v), vector form (sub selects v_pk_add_f32 w/ neg).
__device__ __forceinline__ void resid4v(const f32x2* v, f32x2* l) {
#pragma unroll
    for (int j = 0; j < 4; ++j) {
        f32x2 h;
        h.x = ubits(fbits(v[j].x) & 0xFFFF0000u);   // hi as fp32 (exact)
        h.y = ubits(fbits(v[j].y) & 0xFFFF0000u);
        l[j] = v[j] - h;                            // exact residual
    }
}

__global__ __launch_bounds__(256, 4) void kanv_gemm(
    const float* __restrict__ x,
    const unsigned short* __restrict__ Whi,
    const unsigned short* __restrict__ Wlo,
    const float* __restrict__ bp,
    float* __restrict__ out)
{
    // 9 slabs x 4KB: s=0..4 -> hi p=s ; s=5..8 -> lo p=s-4. 36 KB total.
    __shared__ __align__(16) char sB[9 * 4096];

    const int tid  = threadIdx.x;
    const int lane = tid & 63;
    const int wave = tid >> 6;        // wave = wm (all 4 waves stack on m)
    const int col  = lane & 15;
    const int quad = lane >> 4;

    // XCD swizzle: grid=6272=8*784; bids ==k (mod 8) land on XCD k with contiguous orig range
    // -> all 8 nt-siblings of an mt share one XCD's L2 (x panel reuse).
    const int bid  = blockIdx.x;
    const int orig = (bid & 7) * 784 + (bid >> 3);   // bijective
    const int nt = orig & 7;                          // n-tile (8 x 64 = 512)
    const int mt = orig >> 3;                         // m-tile (784 x 128)
    const int m0 = mt * 128 + wave * 32;

    // per-mi x base: lane holds A[m = m0+mi*16+col][c = g*32+quad*8+j]
    const float* xb[2];
#pragma unroll
    for (int mi = 0; mi < 2; ++mi) {
        int m  = m0 + mi * 16 + col;
        int bb = m / HW3, hw = m - bb * HW3;
        xb[mi] = x + ((size_t)bb * CIN) * HW3 + hw;
    }

    // ---- staging geometry ----
    // slab = 64 rows (n-local) x 32 ch x 2B = 4KB = 4 wave-instructions, i = wave.
    //   src = plane + (nt*64 + wave*16 + col)*2560B + (p*256+g*32)*2B + quad*16B
    //   dst = sB + s*4096 + wave*1024 + lane*16  (DMA: uniform base + lane*16)
    const int voff = (nt * 64 + wave * 16 + col) * 2560 + quad * 16;   // bytes

    // frag-read base: addr = s*4096 + ni*1024 + quad*256 + col*16
    const int rbase = quad * 256 + col * 16;

    f32x4 acc[2][4];
#pragma unroll
    for (int mi = 0; mi < 2; ++mi)
#pragma unroll
        for (int ni = 0; ni < 4; ++ni)
            acc[mi][ni] = (f32x4){0.f, 0.f, 0.f, 0.f};

    f32x2 xv[2][4], pw[2][4], xn[2][4];

    // initial x load (g=0)
#pragma unroll
    for (int mi = 0; mi < 2; ++mi) {
        const float* xp = xb[mi] + (size_t)(quad * 8) * HW3;
#pragma unroll
        for (int j = 0; j < 4; ++j) {
            f32x2 v;
            v.x = xp[(size_t)(2 * j) * HW3];
            v.y = xp[(size_t)(2 * j + 1) * HW3];
            xv[mi][j] = v; pw[mi][j] = v;
        }
    }

    for (int g = 0; g < 8; ++g) {
        __syncthreads();   // prior g's sB reads complete before overwrite

        // ---- stage B slabs for this g (async DMA, 9 instr/wave) ----
#pragma unroll
        for (int s = 0; s < 9; ++s) {
            const unsigned short* plane = (s < 5) ? Whi : Wlo;
            const int p = (s < 5) ? s : (s - 4);
            const char* srcb = (const char*)plane + (size_t)((p * 256 + g * 32) * 2);
            __builtin_amdgcn_global_load_lds(
                (const __attribute__((address_space(1))) void*)(srcb + voff),
                (__attribute__((address_space(3))) void*)(sB + s * 4096 + wave * 1024),
                16, 0, 0);
        }
        __syncthreads();   // compiler drains vmcnt before barrier -> DMA visible to all waves

        // ---- prefetch x for g+1 (consumed ~5 chunks later) ----
        if (g < 7) {
#pragma unroll
            for (int mi = 0; mi < 2; ++mi) {
                const float* xp = xb[mi] + (size_t)((g + 1) * 32 + quad * 8) * HW3;
#pragma unroll
                for (int j = 0; j < 4; ++j) {
                    f32x2 v;
                    v.x = xp[(size_t)(2 * j) * HW3];
                    v.y = xp[(size_t)(2 * j + 1) * HW3];
                    xn[mi][j] = v;
                }
            }
        }

        // ---- compute 5 p-chunks from registers(A) + LDS(B) ----
#pragma unroll
        for (int p = 0; p < 5; ++p) {
            bf16x8 ah[2], al[2];
#pragma unroll
            for (int mi = 0; mi < 2; ++mi) {
                ah[mi] = pack_hi8v(pw[mi]);
                if (p > 0) {
                    f32x2 lo[4];
                    resid4v(pw[mi], lo);
                    al[mi] = pack_hi8v(lo);
                }
            }
            const char* sb_p = sB + p * 4096 + rbase;
            __builtin_amdgcn_s_setprio(1);
#pragma unroll
            for (int ni = 0; ni < 4; ++ni) {
                if (p == 4 && (ni & 1)) continue;            // q-weights zero at p=4
                bf16x8 bh = *(const bf16x8*)(sb_p + ni * 1024);
#pragma unroll
                for (int mi = 0; mi < 2; ++mi)
                    acc[mi][ni] = __builtin_amdgcn_mfma_f32_16x16x32_bf16(ah[mi], bh, acc[mi][ni], 0, 0, 0);
                if (p > 0) {
                    bf16x8 bl = *(const bf16x8*)(sB + (p + 4) * 4096 + rbase + ni * 1024);
#pragma unroll
                    for (int mi = 0; mi < 2; ++mi) {
                        acc[mi][ni] = __builtin_amdgcn_mfma_f32_16x16x32_bf16(al[mi], bh, acc[mi][ni], 0, 0, 0);
                        acc[mi][ni] = __builtin_amdgcn_mfma_f32_16x16x32_bf16(ah[mi], bl, acc[mi][ni], 0, 0, 0);
                    }
                }
            }
            __builtin_amdgcn_s_setprio(0);
            if (p < 4) {
#pragma unroll
                for (int mi = 0; mi < 2; ++mi)
#pragma unroll
                    for (int j = 0; j < 4; ++j)
                        pw[mi][j] *= xv[mi][j];   // next power, fp32 (v_pk_mul_f32)
            }
        }

        if (g < 7) {
#pragma unroll
            for (int mi = 0; mi < 2; ++mi)
#pragma unroll
                for (int j = 0; j < 4; ++j) { xv[mi][j] = xn[mi][j]; pw[mi][j] = xn[mi][j]; }
        }
    }

    // ---- epilogue (verified R2/R3): pair (sum_p, sum_q) frags, bias, divide, float4 store ----
#pragma unroll
    for (int j = 0; j < 2; ++j) {
        const int o = (nt * 2 + j) * 16 + col;
        const float bias = bp[o];
#pragma unroll
        for (int mi = 0; mi < 2; ++mi) {
            f32x4 sp = acc[mi][2 * j];
            f32x4 sq = acc[mi][2 * j + 1];
            const int mrow = m0 + mi * 16 + quad * 4;  // 4 consecutive hw, same image
            const int b2  = mrow / HW3;
            const int hw2 = mrow - b2 * HW3;
            float4 v;
            v.x = (sp[0] + bias) / (1.0f + fabsf(sq[0]));
            v.y = (sp[1] + bias) / (1.0f + fabsf(sq[1]));
            v.z = (sp[2] + bias) / (1.0f + fabsf(sq[2]));
            v.w = (sp[3] + bias) / (1.0f + fabsf(sq[3]));
            *(float4*)&out[((size_t)b2 * 256 + o) * HW3 + hw2] = v;
        }
    }
}

extern "C" void kernel_launch(void* const* d_in, const int* in_sizes, int n_in,
                              void* d_out, int out_size, void* d_ws, size_t ws_size,
                              hipStream_t stream) {
    const float* x  = (const float*)d_in[0];
    const float* Wp = (const float*)d_in[1];
    const float* bp = (const float*)d_in[2];
    const float* Wq = (const float*)d_in[3];
    float* out = (float*)d_out;
    unsigned short* Whi = (unsigned short*)d_ws;              // 1.31 MB
    unsigned short* Wlo = Whi + WPLANE;                        // +1.31 MB

    pack_w_kernel<<<WPLANE / 256, 256, 0, stream>>>(Wp, Wq, Whi, Wlo);
    kanv_gemm<<<(MTOT / 128) * 8, 256, 0, stream>>>(x, Whi, Wlo, bp, out);
}

// Round 4
// 467.074 us; speedup vs baseline: 1.0342x; 1.0342x over previous
//
#include <hip/hip_runtime.h>

// KanvolutionLayer: out[b,o,hw] = (sum_{p,c} x^(p+1) Wp[p,o,c] + bp[o]) / (1 + |sum_{q,c} x^(q+1) Wq[q,o,c]|)
// MFMA GEMM, M=100352 (b*hw), K=1280 (p*256+c), N=512 (p/q outs interleaved per 16).
// R4: 128x128 block, 64x64/wave -> 2 blocks/CU, MfmaUtil 33%, 401 us.
// R5: LDS-A + volatile -> acc spilled (WRITE 3.5GB). Lesson: shrink per-wave tile, don't fight regalloc.
// R6: 128x64 block, 32x64/wave, 9x4KB slabs, 3 blocks/CU: 383 us. VALU 432k + MFMA 333k + bubbles
//     152k = total (pipes ~serial; LDS hides under them). VALU is the largest term.
// R7: bound(256,4)+setprio+f32x2: 400 us. Spill (VGPR 64, WRITE +38MB) + setprio hurt lockstep;
//     f32x2 diet proven (-13% VALU work). Lesson: occupancy gain < spill+setprio cost.
// R8: R6 structure, no setprio, bound(256,3) (no spill), f32x2 state, g-unroll x2 with xvA/xvB
//     rotation: prefetch lands in next-g's buffer (kills 32 copy movs/g), pw-init folded into
//     p0 (packs XV directly; pw=XV*XV is the first update — identical multiply sequence).
//     Drops xn array (-24 regs). VALU -~20% vs R7 codegen.

typedef __attribute__((ext_vector_type(8))) short bf16x8;           // MFMA A/B frag (4 VGPRs)
typedef __attribute__((ext_vector_type(4))) float f32x4;            // MFMA C/D frag
typedef __attribute__((ext_vector_type(2))) float f32x2;            // packed-fp32 pair

#define CIN    256
#define HW3    3136          // 56*56
#define MTOT   100352        // 32*3136 = 784 * 128
#define KTOT   1280
#define WPLANE (512 * 1280)

__device__ __forceinline__ unsigned short f2bf(float f) {
    union { float f; unsigned int u; } cv; cv.f = f;
    unsigned int u = cv.u;
    return (unsigned short)((u + 0x7FFFu + ((u >> 16) & 1u)) >> 16);  // RNE
}
__device__ __forceinline__ float bf2f(unsigned short h) {
    union { unsigned int u; float f; } cv; cv.u = ((unsigned int)h) << 16;
    return cv.f;
}

// Pack weights into bf16 hi/lo planes [512][1280]; row n -> (o,isq):
//   o = (n>>5)*16 + (n&15), isq = (n>>4)&1  (pairs P/Q frags per 16 cols). k = p*256 + c.
__global__ void pack_w_kernel(const float* __restrict__ Wp,
                              const float* __restrict__ Wq,
                              unsigned short* __restrict__ Whi,
                              unsigned short* __restrict__ Wlo) {
    int idx = blockIdx.x * 256 + threadIdx.x;      // [0, 512*1280)
    int n = idx / KTOT;
    int k = idx - n * KTOT;
    int p = k >> 8, c = k & 255;
    int o = ((n >> 5) << 4) + (n & 15);
    int isq = (n >> 4) & 1;
    float v;
    if (isq) v = (p < 4) ? Wq[((size_t)p * 256 + o) * 256 + c] : 0.0f;
    else     v = Wp[((size_t)p * 256 + o) * 256 + c];
    unsigned short h = f2bf(v);
    Whi[idx] = h;
    Wlo[idx] = f2bf(v - bf2f(h));   // exact residual, then one rounding
}

__device__ __forceinline__ unsigned int fbits(float f) {
    union { float f; unsigned int u; } c; c.f = f; return c.u;
}
__device__ __forceinline__ float ubits(unsigned int u) {
    union { unsigned int u; float f; } c; c.u = u; return c.f;
}

// Pack top-16 bits of 4 f32x2 (8 fp32) into a bf16x8 frag (truncation) via v_perm_b32.
__device__ __forceinline__ bf16x8 pack_hi8v(const f32x2* p) {
    union { unsigned int w[4]; bf16x8 h; } r;
#pragma unroll
    for (int j = 0; j < 4; ++j)
        r.w[j] = __builtin_amdgcn_perm(fbits(p[j].y), fbits(p[j].x), 0x07060302);
    return r.h;
}
// Exact residual v - trunc16(v), vector form (sub selects v_pk_add_f32 w/ neg).
__device__ __forceinline__ void resid4v(const f32x2* v, f32x2* l) {
#pragma unroll
    for (int j = 0; j < 4; ++j) {
        f32x2 h;
        h.x = ubits(fbits(v[j].x) & 0xFFFF0000u);   // hi as fp32 (exact)
        h.y = ubits(fbits(v[j].y) & 0xFFFF0000u);
        l[j] = v[j] - h;                            // exact residual
    }
}

__global__ __launch_bounds__(256, 3) void kanv_gemm(
    const float* __restrict__ x,
    const unsigned short* __restrict__ Whi,
    const unsigned short* __restrict__ Wlo,
    const float* __restrict__ bp,
    float* __restrict__ out)
{
    // 9 slabs x 4KB: s=0..4 -> hi p=s ; s=5..8 -> lo p=s-4. 36 KB total.
    __shared__ __align__(16) char sB[9 * 4096];

    const int tid  = threadIdx.x;
    const int lane = tid & 63;
    const int wave = tid >> 6;        // wave = wm (all 4 waves stack on m)
    const int col  = lane & 15;
    const int quad = lane >> 4;

    // XCD swizzle: grid=6272=8*784; bids ==k (mod 8) land on XCD k with contiguous orig range
    // -> all 8 nt-siblings of an mt share one XCD's L2 (x panel reuse).
    const int bid  = blockIdx.x;
    const int orig = (bid & 7) * 784 + (bid >> 3);   // bijective
    const int nt = orig & 7;                          // n-tile (8 x 64 = 512)
    const int mt = orig >> 3;                         // m-tile (784 x 128)
    const int m0 = mt * 128 + wave * 32;

    // per-mi x base: lane holds A[m = m0+mi*16+col][c = g*32+quad*8+j]
    const float* xc[2];
#pragma unroll
    for (int mi = 0; mi < 2; ++mi) {
        int m  = m0 + mi * 16 + col;
        int bb = m / HW3, hw = m - bb * HW3;
        xc[mi] = x + ((size_t)bb * CIN + quad * 8) * HW3 + hw;   // running ptr, += 32*HW3 per g
    }

    // ---- staging geometry ----
    // slab = 64 rows (n-local) x 32 ch x 2B = 4KB = 4 wave-instructions, i = wave.
    //   src = plane + (nt*64 + wave*16 + col)*2560B + (p*256+g*32)*2B + quad*16B
    //   dst = sB + s*4096 + wave*1024 + lane*16  (DMA: uniform base + lane*16)
    const int voff = (nt * 64 + wave * 16 + col) * 2560 + quad * 16;   // bytes

    // frag-read base: addr = s*4096 + ni*1024 + quad*256 + col*16
    const int rbase = quad * 256 + col * 16;

    f32x4 acc[2][4];
#pragma unroll
    for (int mi = 0; mi < 2; ++mi)
#pragma unroll
        for (int ni = 0; ni < 4; ++ni)
            acc[mi][ni] = (f32x4){0.f, 0.f, 0.f, 0.f};

    f32x2 xvA[2][4], xvB[2][4];

    // initial x load (g=0) into xvA
#pragma unroll
    for (int mi = 0; mi < 2; ++mi) {
#pragma unroll
        for (int j = 0; j < 4; ++j) {
            f32x2 v;
            v.x = xc[mi][(size_t)(2 * j) * HW3];
            v.y = xc[mi][(size_t)(2 * j + 1) * HW3];
            xvA[mi][j] = v;
        }
        xc[mi] += (size_t)32 * HW3;
    }

    // One g-step. XV: this g's x (consumed). XN: buffer for g+1's x (prefetched).
    auto body = [&](int g, f32x2 (&XV)[2][4], f32x2 (&XN)[2][4]) {
        __syncthreads();   // prior g's sB reads complete before overwrite

        // ---- stage B slabs for this g (async DMA, 9 instr/wave) ----
#pragma unroll
        for (int s = 0; s < 9; ++s) {
            const unsigned short* plane = (s < 5) ? Whi : Wlo;
            const int p = (s < 5) ? s : (s - 4);
            const char* srcb = (const char*)plane + (size_t)((p * 256 + g * 32) * 2);
            __builtin_amdgcn_global_load_lds(
                (const __attribute__((address_space(1))) void*)(srcb + voff),
                (__attribute__((address_space(3))) void*)(sB + s * 4096 + wave * 1024),
                16, 0, 0);
        }
        __syncthreads();   // compiler drains vmcnt before barrier -> DMA visible to all waves

        // ---- prefetch x for g+1 directly into the next-g buffer (no copy at g end) ----
        if (g < 7) {
#pragma unroll
            for (int mi = 0; mi < 2; ++mi) {
#pragma unroll
                for (int j = 0; j < 4; ++j) {
                    f32x2 v;
                    v.x = xc[mi][(size_t)(2 * j) * HW3];
                    v.y = xc[mi][(size_t)(2 * j + 1) * HW3];
                    XN[mi][j] = v;
                }
                xc[mi] += (size_t)32 * HW3;
            }
        }

        // ---- compute 5 p-chunks from registers(A) + LDS(B) ----
        // p0 packs XV (x^1) directly; pw = XV*XV is the first power update (x^2) —
        // identical fp32 multiply sequence to pw-init+update, without the init copy.
        f32x2 pw[2][4];
#pragma unroll
        for (int p = 0; p < 5; ++p) {
            bf16x8 ah[2], al[2];
#pragma unroll
            for (int mi = 0; mi < 2; ++mi) {
                const f32x2* src = (p == 0) ? XV[mi] : pw[mi];
                ah[mi] = pack_hi8v(src);
                if (p > 0) {
                    f32x2 lo[4];
                    resid4v(pw[mi], lo);
                    al[mi] = pack_hi8v(lo);
                }
            }
            const char* sb_p = sB + p * 4096 + rbase;
#pragma unroll
            for (int ni = 0; ni < 4; ++ni) {
                if (p == 4 && (ni & 1)) continue;            // q-weights zero at p=4
                bf16x8 bh = *(const bf16x8*)(sb_p + ni * 1024);
#pragma unroll
                for (int mi = 0; mi < 2; ++mi)
                    acc[mi][ni] = __builtin_amdgcn_mfma_f32_16x16x32_bf16(ah[mi], bh, acc[mi][ni], 0, 0, 0);
                if (p > 0) {
                    bf16x8 bl = *(const bf16x8*)(sB + (p + 4) * 4096 + rbase + ni * 1024);
#pragma unroll
                    for (int mi = 0; mi < 2; ++mi) {
                        acc[mi][ni] = __builtin_amdgcn_mfma_f32_16x16x32_bf16(al[mi], bh, acc[mi][ni], 0, 0, 0);
                        acc[mi][ni] = __builtin_amdgcn_mfma_f32_16x16x32_bf16(ah[mi], bl, acc[mi][ni], 0, 0, 0);
                    }
                }
            }
            if (p < 4) {
#pragma unroll
                for (int mi = 0; mi < 2; ++mi)
#pragma unroll
                    for (int j = 0; j < 4; ++j)
                        pw[mi][j] = (p == 0) ? (XV[mi][j] * XV[mi][j])     // x^2
                                             : (pw[mi][j] * XV[mi][j]);    // next power (v_pk_mul_f32)
            }
        }
    };

    // g-loop unrolled x2 with buffer rotation: even g reads xvA / prefetches xvB, odd swaps.
    for (int gg = 0; gg < 4; ++gg) {
        body(2 * gg,     xvA, xvB);
        body(2 * gg + 1, xvB, xvA);
    }

    // ---- epilogue (verified R2/R3): pair (sum_p, sum_q) frags, bias, divide, float4 store ----
#pragma unroll
    for (int j = 0; j < 2; ++j) {
        const int o = (nt * 2 + j) * 16 + col;
        const float bias = bp[o];
#pragma unroll
        for (int mi = 0; mi < 2; ++mi) {
            f32x4 sp = acc[mi][2 * j];
            f32x4 sq = acc[mi][2 * j + 1];
            const int mrow = m0 + mi * 16 + quad * 4;  // 4 consecutive hw, same image
            const int b2  = mrow / HW3;
            const int hw2 = mrow - b2 * HW3;
            float4 v;
            v.x = (sp[0] + bias) / (1.0f + fabsf(sq[0]));
            v.y = (sp[1] + bias) / (1.0f + fabsf(sq[1]));
            v.z = (sp[2] + bias) / (1.0f + fabsf(sq[2]));
            v.w = (sp[3] + bias) / (1.0f + fabsf(sq[3]));
            *(float4*)&out[((size_t)b2 * 256 + o) * HW3 + hw2] = v;
        }
    }
}

extern "C" void kernel_launch(void* const* d_in, const int* in_sizes, int n_in,
                              void* d_out, int out_size, void* d_ws, size_t ws_size,
                              hipStream_t stream) {
    const float* x  = (const float*)d_in[0];
    const float* Wp = (const float*)d_in[1];
    const float* bp = (const float*)d_in[2];
    const float* Wq = (const float*)d_in[3];
    float* out = (float*)d_out;
    unsigned short* Whi = (unsigned short*)d_ws;              // 1.31 MB
    unsigned short* Wlo = Whi + WPLANE;                        // +1.31 MB

    pack_w_kernel<<<WPLANE / 256, 256, 0, stream>>>(Wp, Wq, Whi, Wlo);
    kanv_gemm<<<(MTOT / 128) * 8, 256, 0, stream>>>(x, Whi, Wlo, bp, out);
}

// Round 5
// 463.618 us; speedup vs baseline: 1.0419x; 1.0075x over previous
//
#include <hip/hip_runtime.h>

// KanvolutionLayer: out[b,o,hw] = (sum_{p,c} x^(p+1) Wp[p,o,c] + bp[o]) / (1 + |sum_{q,c} x^(q+1) Wq[q,o,c]|)
// MFMA GEMM, M=100352 (b*hw), K=1280 (p*256+c), N=512 (p/q outs interleaved per 16).
// R4: 128x128 block, 64x64/wave -> 2 blocks/CU, MfmaUtil 33%, 401 us.
// R5: LDS-A + volatile -> acc spilled (WRITE 3.5GB). Lesson: shrink per-wave tile, don't fight regalloc.
// R6: 128x64 block, 32x64/wave, 9x4KB slabs, 3 blocks/CU: 383 us.
// R7: bound(256,4)+setprio: spilled (VGPR 64) + setprio hurt lockstep: 400 us. f32x2 diet kept.
// R8: f32x2 + xvA/xvB rotation + folded pw-init: 377 us. Ledger: VALU 362k + MFMA 339k +
//     bubbles 205k = wall 906k per SIMD -> pipes STRICTLY SERIAL per wave; pack(p)->MFMA(p)
//     adjacency is the dependency that forces it.
// R9: software-pipeline: pre-pack ahC/alC for p, compute ahN/alN (+pw update) for p+1 as an
//     INDEPENDENT VALU cluster next to MFMA(p), rotate. Identical arithmetic/rounding; only the
//     dep graph changes. Scheduler can put ~35 VALU ops in the 19.4-cyc gaps between MFMAs.
//     +16 VGPR (second frag set) -- stays 3 blocks/CU at bound(256,3).

typedef __attribute__((ext_vector_type(8))) short bf16x8;           // MFMA A/B frag (4 VGPRs)
typedef __attribute__((ext_vector_type(4))) float f32x4;            // MFMA C/D frag
typedef __attribute__((ext_vector_type(2))) float f32x2;            // packed-fp32 pair

#define CIN    256
#define HW3    3136          // 56*56
#define MTOT   100352        // 32*3136 = 784 * 128
#define KTOT   1280
#define WPLANE (512 * 1280)

__device__ __forceinline__ unsigned short f2bf(float f) {
    union { float f; unsigned int u; } cv; cv.f = f;
    unsigned int u = cv.u;
    return (unsigned short)((u + 0x7FFFu + ((u >> 16) & 1u)) >> 16);  // RNE
}
__device__ __forceinline__ float bf2f(unsigned short h) {
    union { unsigned int u; float f; } cv; cv.u = ((unsigned int)h) << 16;
    return cv.f;
}

// Pack weights into bf16 hi/lo planes [512][1280]; row n -> (o,isq):
//   o = (n>>5)*16 + (n&15), isq = (n>>4)&1  (pairs P/Q frags per 16 cols). k = p*256 + c.
__global__ void pack_w_kernel(const float* __restrict__ Wp,
                              const float* __restrict__ Wq,
                              unsigned short* __restrict__ Whi,
                              unsigned short* __restrict__ Wlo) {
    int idx = blockIdx.x * 256 + threadIdx.x;      // [0, 512*1280)
    int n = idx / KTOT;
    int k = idx - n * KTOT;
    int p = k >> 8, c = k & 255;
    int o = ((n >> 5) << 4) + (n & 15);
    int isq = (n >> 4) & 1;
    float v;
    if (isq) v = (p < 4) ? Wq[((size_t)p * 256 + o) * 256 + c] : 0.0f;
    else     v = Wp[((size_t)p * 256 + o) * 256 + c];
    unsigned short h = f2bf(v);
    Whi[idx] = h;
    Wlo[idx] = f2bf(v - bf2f(h));   // exact residual, then one rounding
}

__device__ __forceinline__ unsigned int fbits(float f) {
    union { float f; unsigned int u; } c; c.f = f; return c.u;
}
__device__ __forceinline__ float ubits(unsigned int u) {
    union { unsigned int u; float f; } c; c.u = u; return c.f;
}

// Pack top-16 bits of 4 f32x2 (8 fp32) into a bf16x8 frag (truncation) via v_perm_b32.
__device__ __forceinline__ bf16x8 pack_hi8v(const f32x2* p) {
    union { unsigned int w[4]; bf16x8 h; } r;
#pragma unroll
    for (int j = 0; j < 4; ++j)
        r.w[j] = __builtin_amdgcn_perm(fbits(p[j].y), fbits(p[j].x), 0x07060302);
    return r.h;
}
// Exact residual v - trunc16(v), vector form (sub selects v_pk_add_f32 w/ neg).
__device__ __forceinline__ void resid4v(const f32x2* v, f32x2* l) {
#pragma unroll
    for (int j = 0; j < 4; ++j) {
        f32x2 h;
        h.x = ubits(fbits(v[j].x) & 0xFFFF0000u);   // hi as fp32 (exact)
        h.y = ubits(fbits(v[j].y) & 0xFFFF0000u);
        l[j] = v[j] - h;                            // exact residual
    }
}

__global__ __launch_bounds__(256, 3) void kanv_gemm(
    const float* __restrict__ x,
    const unsigned short* __restrict__ Whi,
    const unsigned short* __restrict__ Wlo,
    const float* __restrict__ bp,
    float* __restrict__ out)
{
    // 9 slabs x 4KB: s=0..4 -> hi p=s ; s=5..8 -> lo p=s-4. 36 KB total.
    __shared__ __align__(16) char sB[9 * 4096];

    const int tid  = threadIdx.x;
    const int lane = tid & 63;
    const int wave = tid >> 6;        // wave = wm (all 4 waves stack on m)
    const int col  = lane & 15;
    const int quad = lane >> 4;

    // XCD swizzle: grid=6272=8*784; bids ==k (mod 8) land on XCD k with contiguous orig range
    // -> all 8 nt-siblings of an mt share one XCD's L2 (x panel reuse).
    const int bid  = blockIdx.x;
    const int orig = (bid & 7) * 784 + (bid >> 3);   // bijective
    const int nt = orig & 7;                          // n-tile (8 x 64 = 512)
    const int mt = orig >> 3;                         // m-tile (784 x 128)
    const int m0 = mt * 128 + wave * 32;

    // per-mi x base: lane holds A[m = m0+mi*16+col][c = g*32+quad*8+j]
    const float* xc[2];
#pragma unroll
    for (int mi = 0; mi < 2; ++mi) {
        int m  = m0 + mi * 16 + col;
        int bb = m / HW3, hw = m - bb * HW3;
        xc[mi] = x + ((size_t)bb * CIN + quad * 8) * HW3 + hw;   // running ptr, += 32*HW3 per g
    }

    // ---- staging geometry ----
    // slab = 64 rows (n-local) x 32 ch x 2B = 4KB = 4 wave-instructions, i = wave.
    //   src = plane + (nt*64 + wave*16 + col)*2560B + (p*256+g*32)*2B + quad*16B
    //   dst = sB + s*4096 + wave*1024 + lane*16  (DMA: uniform base + lane*16)
    const int voff = (nt * 64 + wave * 16 + col) * 2560 + quad * 16;   // bytes

    // frag-read base: addr = s*4096 + ni*1024 + quad*256 + col*16
    const int rbase = quad * 256 + col * 16;

    f32x4 acc[2][4];
#pragma unroll
    for (int mi = 0; mi < 2; ++mi)
#pragma unroll
        for (int ni = 0; ni < 4; ++ni)
            acc[mi][ni] = (f32x4){0.f, 0.f, 0.f, 0.f};

    f32x2 xvA[2][4], xvB[2][4];

    // initial x load (g=0) into xvA
#pragma unroll
    for (int mi = 0; mi < 2; ++mi) {
#pragma unroll
        for (int j = 0; j < 4; ++j) {
            f32x2 v;
            v.x = xc[mi][(size_t)(2 * j) * HW3];
            v.y = xc[mi][(size_t)(2 * j + 1) * HW3];
            xvA[mi][j] = v;
        }
        xc[mi] += (size_t)32 * HW3;
    }

    // One g-step. XV: this g's x (consumed). XN: buffer for g+1's x (prefetched).
    auto body = [&](int g, f32x2 (&XV)[2][4], f32x2 (&XN)[2][4]) {
        __syncthreads();   // prior g's sB reads complete before overwrite

        // ---- stage B slabs for this g (async DMA, 9 instr/wave) ----
#pragma unroll
        for (int s = 0; s < 9; ++s) {
            const unsigned short* plane = (s < 5) ? Whi : Wlo;
            const int p = (s < 5) ? s : (s - 4);
            const char* srcb = (const char*)plane + (size_t)((p * 256 + g * 32) * 2);
            __builtin_amdgcn_global_load_lds(
                (const __attribute__((address_space(1))) void*)(srcb + voff),
                (__attribute__((address_space(3))) void*)(sB + s * 4096 + wave * 1024),
                16, 0, 0);
        }
        __syncthreads();   // compiler drains vmcnt before barrier -> DMA visible to all waves

        // ---- prefetch x for g+1 directly into the next-g buffer (no copy at g end) ----
        if (g < 7) {
#pragma unroll
            for (int mi = 0; mi < 2; ++mi) {
#pragma unroll
                for (int j = 0; j < 4; ++j) {
                    f32x2 v;
                    v.x = xc[mi][(size_t)(2 * j) * HW3];
                    v.y = xc[mi][(size_t)(2 * j + 1) * HW3];
                    XN[mi][j] = v;
                }
                xc[mi] += (size_t)32 * HW3;
            }
        }

        // ---- compute 5 p-chunks, software-pipelined: MFMA(p) runs on pre-packed ahC/alC
        //      while the VALU cluster builds ahN/alN for p+1 (independent -> scheduler
        //      interleaves VALU into the 19.4-cyc gaps between MFMAs). Same arithmetic
        //      sequence as R8 (pack/resid/pw-update ops identical, just reordered deps).
        f32x2 pw[2][4];
        bf16x8 ahC[2], alC[2];
#pragma unroll
        for (int mi = 0; mi < 2; ++mi) {
            ahC[mi] = pack_hi8v(XV[mi]);                       // p=0 operand: x^1 (no lo)
#pragma unroll
            for (int j = 0; j < 4; ++j)
                pw[mi][j] = XV[mi][j] * XV[mi][j];             // x^2 for p=1 (v_pk_mul_f32)
        }
#pragma unroll
        for (int p = 0; p < 5; ++p) {
            // -- independent VALU cluster: pack operands for p+1 from pw = x^(p+2) --
            bf16x8 ahN[2], alN[2];
            if (p < 4) {
#pragma unroll
                for (int mi = 0; mi < 2; ++mi) {
                    ahN[mi] = pack_hi8v(pw[mi]);
                    f32x2 lo[4];
                    resid4v(pw[mi], lo);
                    alN[mi] = pack_hi8v(lo);
                }
                if (p < 3) {
#pragma unroll
                    for (int mi = 0; mi < 2; ++mi)
#pragma unroll
                        for (int j = 0; j < 4; ++j)
                            pw[mi][j] *= XV[mi][j];            // x^(p+3) for the next prepack
                }
            }
            // -- MFMA cluster for p (consumes ahC/alC, independent of the VALU above) --
            const char* sb_p = sB + p * 4096 + rbase;
#pragma unroll
            for (int ni = 0; ni < 4; ++ni) {
                if (p == 4 && (ni & 1)) continue;              // q-weights zero at p=4
                bf16x8 bh = *(const bf16x8*)(sb_p + ni * 1024);
#pragma unroll
                for (int mi = 0; mi < 2; ++mi)
                    acc[mi][ni] = __builtin_amdgcn_mfma_f32_16x16x32_bf16(ahC[mi], bh, acc[mi][ni], 0, 0, 0);
                if (p > 0) {
                    bf16x8 bl = *(const bf16x8*)(sB + (p + 4) * 4096 + rbase + ni * 1024);
#pragma unroll
                    for (int mi = 0; mi < 2; ++mi) {
                        acc[mi][ni] = __builtin_amdgcn_mfma_f32_16x16x32_bf16(alC[mi], bh, acc[mi][ni], 0, 0, 0);
                        acc[mi][ni] = __builtin_amdgcn_mfma_f32_16x16x32_bf16(ahC[mi], bl, acc[mi][ni], 0, 0, 0);
                    }
                }
            }
            // rotate (register renames, no movs after unroll)
#pragma unroll
            for (int mi = 0; mi < 2; ++mi) { ahC[mi] = ahN[mi]; alC[mi] = alN[mi]; }
        }
    };

    // g-loop unrolled x2 with buffer rotation: even g reads xvA / prefetches xvB, odd swaps.
    for (int gg = 0; gg < 4; ++gg) {
        body(2 * gg,     xvA, xvB);
        body(2 * gg + 1, xvB, xvA);
    }

    // ---- epilogue (verified R2/R3): pair (sum_p, sum_q) frags, bias, divide, float4 store ----
#pragma unroll
    for (int j = 0; j < 2; ++j) {
        const int o = (nt * 2 + j) * 16 + col;
        const float bias = bp[o];
#pragma unroll
        for (int mi = 0; mi < 2; ++mi) {
            f32x4 sp = acc[mi][2 * j];
            f32x4 sq = acc[mi][2 * j + 1];
            const int mrow = m0 + mi * 16 + quad * 4;  // 4 consecutive hw, same image
            const int b2  = mrow / HW3;
            const int hw2 = mrow - b2 * HW3;
            float4 v;
            v.x = (sp[0] + bias) / (1.0f + fabsf(sq[0]));
            v.y = (sp[1] + bias) / (1.0f + fabsf(sq[1]));
            v.z = (sp[2] + bias) / (1.0f + fabsf(sq[2]));
            v.w = (sp[3] + bias) / (1.0f + fabsf(sq[3]));
            *(float4*)&out[((size_t)b2 * 256 + o) * HW3 + hw2] = v;
        }
    }
}

extern "C" void kernel_launch(void* const* d_in, const int* in_sizes, int n_in,
                              void* d_out, int out_size, void* d_ws, size_t ws_size,
                              hipStream_t stream) {
    const float* x  = (const float*)d_in[0];
    const float* Wp = (const float*)d_in[1];
    const float* bp = (const float*)d_in[2];
    const float* Wq = (const float*)d_in[3];
    float* out = (float*)d_out;
    unsigned short* Whi = (unsigned short*)d_ws;              // 1.31 MB
    unsigned short* Wlo = Whi + WPLANE;                        // +1.31 MB

    pack_w_kernel<<<WPLANE / 256, 256, 0, stream>>>(Wp, Wq, Whi, Wlo);
    kanv_gemm<<<(MTOT / 128) * 8, 256, 0, stream>>>(x, Whi, Wlo, bp, out);
}